// Round 1
// baseline (22.743 us; speedup 1.0000x reference)
//
#include <hip/hip_runtime.h>
#include <hip/hip_bf16.h>
#include <math.h>

// Problem shape (from setup_inputs): pred/targ f32 [B=4096, H=128, D=64].
// Output: single f32 scalar (weighted mean loss).
//
// Key insight: only row h = idx (idx = t-1, or H-1 if t==0) of (loss+loss1)
// contributes per sample, where t = count_nonzero(targ[i,:,1]).
// total[i,idx,d] = diff^2 + |diff - prev_diff|, with
//   diff      = pred[i,idx,d]  - targ[i,idx,d]
//   prev_diff = (idx>=1) ? pred[i,idx-1,d] - targ[i,idx-1,d] : 0
// per_sample[i] = (1 + 0.5*(t/(H-1))^2.5) * sum_d total[i,idx,d]
// out = mean_i per_sample[i]

#define H_DIM 128
#define D_DIM 64

__global__ __launch_bounds__(128) void wsl_per_sample_kernel(
    const float* __restrict__ pred,
    const float* __restrict__ targ,
    float* __restrict__ per_sample)
{
    const int i   = blockIdx.x;
    const int tid = threadIdx.x;
    const long long base = (long long)i * (H_DIM * D_DIM);

    // ---- phase 1: t = count of nonzero targ[i, h, 1] over h = 0..H-1 ----
    // 128 threads, one h each; strided load (stride = D_DIM floats).
    float v = targ[base + (long long)tid * D_DIM + 1];
    int flag = (v != 0.0f) ? 1 : 0;

    // per-wave ballot (wave = 64 lanes), combine the two waves via LDS
    unsigned long long mask = __ballot(flag);
    __shared__ int wave_cnt[2];
    if ((tid & 63) == 0) wave_cnt[tid >> 6] = __popcll(mask);
    __syncthreads();
    const int t = wave_cnt[0] + wave_cnt[1];

    int idx = t - 1;
    if (idx < 0) idx = H_DIM - 1;   // torch negative-index mimic

    // ---- phase 2: row reduction over d = 0..63 (wave 0 only) ----
    if (tid < 64) {
        const long long off = base + (long long)idx * D_DIM + tid;
        const float dcur = pred[off] - targ[off];
        float dprev = 0.0f;
        if (idx >= 1) {
            const long long offp = off - D_DIM;
            dprev = pred[offp] - targ[offp];
        }
        float sum = dcur * dcur + fabsf(dcur - dprev);

        // wave-64 tree reduce
        #pragma unroll
        for (int sh = 32; sh >= 1; sh >>= 1)
            sum += __shfl_down(sum, sh, 64);

        if (tid == 0) {
            const float tf = (float)t / (float)(H_DIM - 1);
            const float w  = 1.0f + 0.5f * powf(tf, 2.5f);
            per_sample[i] = w * sum;
        }
    }
}

__global__ __launch_bounds__(256) void wsl_finalize_kernel(
    const float* __restrict__ per_sample,
    float* __restrict__ out,
    int B)
{
    __shared__ float s[256];
    const int tid = threadIdx.x;
    float acc = 0.0f;
    // fixed iteration order -> deterministic
    for (int j = tid; j < B; j += 256) acc += per_sample[j];
    s[tid] = acc;
    __syncthreads();
    #pragma unroll
    for (int stride = 128; stride >= 1; stride >>= 1) {
        if (tid < stride) s[tid] += s[tid + stride];
        __syncthreads();
    }
    if (tid == 0) out[0] = s[0] / (float)B;
}

extern "C" void kernel_launch(void* const* d_in, const int* in_sizes, int n_in,
                              void* d_out, int out_size, void* d_ws, size_t ws_size,
                              hipStream_t stream)
{
    const float* pred = (const float*)d_in[0];
    const float* targ = (const float*)d_in[1];
    float* out = (float*)d_out;

    const int B = in_sizes[0] / (H_DIM * D_DIM);   // 4096

    float* per_sample = (float*)d_ws;              // B floats of scratch

    wsl_per_sample_kernel<<<B, 128, 0, stream>>>(pred, targ, per_sample);
    wsl_finalize_kernel<<<1, 256, 0, stream>>>(per_sample, out, B);
}